// Round 12
// baseline (301.549 us; speedup 1.0000x reference)
//
#include <hip/hip_runtime.h>
#include <hip/hip_bf16.h>

typedef _Float16 half8  __attribute__((ext_vector_type(8)));
typedef _Float16 half4v __attribute__((ext_vector_type(4)));
typedef float    f32x4  __attribute__((ext_vector_type(4)));

#define N_NODES 100000
#define N_EDGES 3200000
#define SH_STRIDE 100096   // fallback shadow stride (floats)
#define NBUCK 782          // 128 nodes per bucket == one sage tile
#define CAP   5120         // records/bucket: mean 4092 + 16 sigma
#define CHUNK 4096         // edges per bin block (512 thr x 2 x int4)
#define NBIN  782          // ceil(N_EDGES/CHUNK)
#define NPK   32           // pack blocks appended to bin grid

// ---------------------------------------------------------------------------
// Bin + pack kernel (R5 version, unchanged). Pack phase writes Wp in
// MFMA-FRAGMENT-MAJOR order:
//   Wp[layer_off + w*64*K + (s*4 + j)*512 + lane*8 + e]
//     = W[w*64 + j*16 + (lane&15)][s*32 + (lane>>4)*8 + e]
// R5 measured: coalescing the a-loads cut sage 159->134 us. R12 consumes
// the SAME layout: a wave's 128 cols = slices w=2*wc and 2*wc+1.
// ---------------------------------------------------------------------------
__global__ __launch_bounds__(512) void binpack(
    const float* __restrict__ ef, const int* __restrict__ dst,
    const float* __restrict__ W1,  const float* __restrict__ Wm1,
    const float* __restrict__ Wm2, const float* __restrict__ Wm3,
    const float* __restrict__ Wm4, const float* __restrict__ Wr1,
    const float* __restrict__ Wr2,
    const float* __restrict__ b1,  const float* __restrict__ bm1,
    const float* __restrict__ bm2, const float* __restrict__ bm3,
    const float* __restrict__ bm4, const float* __restrict__ br1,
    const float* __restrict__ br2, const float* __restrict__ wr3,
    const float* __restrict__ br3,
    int* __restrict__ cursor, unsigned* __restrict__ pairs,
    _Float16* __restrict__ Wp, float* __restrict__ park, int do_bin) {

    if (do_bin && blockIdx.x < NBIN) {
        __shared__ int      hist[NBUCK];
        __shared__ int      base[NBUCK];   // absolute global base per bucket
        __shared__ int      lbase[NBUCK];  // LDS group base per bucket
        __shared__ int      wsum[8];       // per-wave scan totals
        __shared__ unsigned lrec[CHUNK];   // grouped records
        __shared__ int      lslot[CHUNK];  // grouped global slots (-1 = drop)
        const int start = blockIdx.x * CHUNK;
        const int tid   = threadIdx.x;
        const int wave  = tid >> 6;
        const int lane  = tid & 63;
        for (int b = tid; b < NBUCK; b += 512) hist[b] = 0;
        __syncthreads();

        // phase1: histogram; keep each edge's rank in registers
        int4   dreg[2];
        float4 freg[2];
        int    rnk[2][4];
        #pragma unroll
        for (int it = 0; it < 2; ++it) {
            const int i = start + (it * 512 + tid) * 4;
            if (i < N_EDGES) {
                dreg[it] = *(const int4*)&dst[i];
                freg[it] = *(const float4*)&ef[i];
                rnk[it][0] = atomicAdd(&hist[dreg[it].x >> 7], 1);
                rnk[it][1] = atomicAdd(&hist[dreg[it].y >> 7], 1);
                rnk[it][2] = atomicAdd(&hist[dreg[it].z >> 7], 1);
                rnk[it][3] = atomicAdd(&hist[dreg[it].w >> 7], 1);
            }
        }
        __syncthreads();

        // reserve global space (one atomic per nonzero bucket)
        for (int b = tid; b < NBUCK; b += 512) {
            const int c = hist[b];
            base[b] = b * CAP + ((c > 0) ? atomicAdd(&cursor[b], c) : 0);
        }
        // scan: thread owns buckets 2t, 2t+1; wave shfl prefix + fixup
        const int b0 = 2 * tid, b1 = 2 * tid + 1;
        const int h0 = (b0 < NBUCK) ? hist[b0] : 0;
        const int h1 = (b1 < NBUCK) ? hist[b1] : 0;
        const int psum = h0 + h1;
        int pfx = psum;
        #pragma unroll
        for (int ofs = 1; ofs < 64; ofs <<= 1) {
            const int v = __shfl_up(pfx, ofs);
            if (lane >= ofs) pfx += v;
        }
        if (lane == 63) wsum[wave] = pfx;
        __syncthreads();
        int woff = 0;
        #pragma unroll
        for (int w = 0; w < 8; ++w) woff += (w < wave) ? wsum[w] : 0;
        const int excl = woff + pfx - psum;   // exclusive prefix of bucket b0
        if (b0 < NBUCK) lbase[b0] = excl;
        if (b1 < NBUCK) lbase[b1] = excl + h0;
        __syncthreads();

        // phase2: place into LDS grouped by bucket (saved ranks, no atomics)
        #pragma unroll
        for (int it = 0; it < 2; ++it) {
            const int i = start + (it * 512 + tid) * 4;
            if (i < N_EDGES) {
                const int4   d = dreg[it];
                const float4 f = freg[it];
                {   const int bk = d.x >> 7; const int r = rnk[it][0];
                    const int s = lbase[bk] + r; const int g = base[bk] + r;
                    lrec[s]  = (__float_as_uint(f.x) & 0xFFFFFF00u) | (unsigned)(d.x & 127);
                    lslot[s] = (g < (bk + 1) * CAP) ? g : -1; }
                {   const int bk = d.y >> 7; const int r = rnk[it][1];
                    const int s = lbase[bk] + r; const int g = base[bk] + r;
                    lrec[s]  = (__float_as_uint(f.y) & 0xFFFFFF00u) | (unsigned)(d.y & 127);
                    lslot[s] = (g < (bk + 1) * CAP) ? g : -1; }
                {   const int bk = d.z >> 7; const int r = rnk[it][2];
                    const int s = lbase[bk] + r; const int g = base[bk] + r;
                    lrec[s]  = (__float_as_uint(f.z) & 0xFFFFFF00u) | (unsigned)(d.z & 127);
                    lslot[s] = (g < (bk + 1) * CAP) ? g : -1; }
                {   const int bk = d.w >> 7; const int r = rnk[it][3];
                    const int s = lbase[bk] + r; const int g = base[bk] + r;
                    lrec[s]  = (__float_as_uint(f.w) & 0xFFFFFF00u) | (unsigned)(d.w & 127);
                    lslot[s] = (g < (bk + 1) * CAP) ? g : -1; }
            }
        }
        __syncthreads();
        // phase3: coalesced run writes
        const int total = min(CHUNK, N_EDGES - start);
        for (int s = tid; s < total; s += 512) {
            const int g = lslot[s];
            if (g >= 0) pairs[g] = lrec[s];
        }
    } else {
        const float* srcs[7] = {W1, Wm1, Wm2, Wm3, Wm4, Wr1, Wr2};
        const float* bias[7] = {b1, bm1, bm2, bm3, bm4, br1, br2};
        const int pb  = do_bin ? ((int)blockIdx.x - NBIN) : (int)blockIdx.x;
        const int gid = pb * 512 + threadIdx.x;
        const int gsz = NPK * 512;
        // fragment-major weight pack (see header comment)
        for (int i = gid; i < 425984; i += gsz) {
            int job, w, s, j, lane, e, stride;
            if (i < 32768) {            // layer 0, K=128 (4 ksteps/wave)
                job = 0; stride = 129;
                w = i >> 13;            // 8192 halfs per col-slice
                const int rem = i & 8191;
                s = rem >> 11;          // 2048 halfs per kstep
                j = (rem >> 9) & 3;
                lane = (rem >> 3) & 63;
                e = rem & 7;
            } else {                    // layers 1..6, K=256 (8 ksteps/wave)
                const int t = i - 32768;
                job = 1 + (t >> 16);
                const int local = t & 65535;
                stride = (job == 6) ? 256 : 257;
                w = local >> 14;        // 16384 halfs per col-slice
                const int rem = local & 16383;
                s = rem >> 11;
                j = (rem >> 9) & 3;
                lane = (rem >> 3) & 63;
                e = rem & 7;
            }
            const int row = w * 64 + j * 16 + (lane & 15);
            const int col = s * 32 + ((lane >> 4) << 3) + e;
            Wp[i] = (_Float16)srcs[job][row * stride + col];
        }
        for (int i = gid; i < 1536; i += gsz) {
            const int job = i >> 8, row = i & 255;
            const int stride = (job == 0) ? 129 : 257;
            const int kin    = (job == 0) ? 128 : 256;
            park[job * 512 + row] = srcs[job][row * stride + kin];
        }
        for (int i = gid; i < 256; i += gsz) park[6 * 512 + i] = 0.f;
        for (int i = gid; i < 1792; i += gsz)
            park[(i >> 8) * 512 + 256 + (i & 255)] = bias[i >> 8][i & 255];
        for (int i = gid; i < 256; i += gsz) park[3584 + i] = wr3[i];
        if (gid == 0) park[3840] = br3[0];
    }
}

// fallback: device-scope split-4 scatter (known-good)
__global__ void scatter4(const float4* __restrict__ ef4,
                         const int4* __restrict__ dst4,
                         float* __restrict__ e) {
    const int n4 = N_EDGES / 4;
    for (int i = blockIdx.x * blockDim.x + threadIdx.x; i < n4;
         i += gridDim.x * blockDim.x) {
        const float4 f = ef4[i];
        const int4   d = dst4[i];
        atomicAdd(&e[d.x], f.x);
        atomicAdd(&e[SH_STRIDE + d.y], f.y);
        atomicAdd(&e[2 * SH_STRIDE + d.z], f.z);
        atomicAdd(&e[3 * SH_STRIDE + d.w], f.w);
    }
}

// ---------------------------------------------------------------------------
// R12: 2x2 WAVE SPLIT (wave = 128 cols x 64 rows, acc[8][4]) to HALVE the
// redundant b-reads. In the 4-col-slice champion, all 4 waves read the
// IDENTICAL Hs b-fragments (the read address never involves `wave`) -> 4x
// redundant LDS traffic, the heaviest pipe (~9K cyc/CU/layer). 2 col-halves
// x 2 row-halves cuts b-redundancy to 2x (LDS reads halve) at the cost of
// 2x a-redundancy on L2 (affordable: W is L2-resident, ~40% of per-XCD BW).
// Same Wp pack (wave's cols = slices 2wc, 2wc+1), same 128-VGPR acc, same
// barrier structure. a[8] ring-reloaded after use (R10 trick, ~28-MFMA gap
// covers L2 latency); b[4]+b2[4] double-buffered -> 192 live regs, identical
// pressure to champion. Axis history: spill (R4) exonerated; occupancy
// (R1/R7/R8) closed; swizzle (R9) refuted; b-pipeline (R10) neutral.
// ---------------------------------------------------------------------------
template<int K>
__device__ __forceinline__ void layer_mm(const _Float16* __restrict__ Wl,
                                         _Float16 (* __restrict__ Hs)[264],
                                         const float* __restrict__ es,
                                         const float* __restrict__ parkl,
                                         int wave, int lane, int m_, int quad) {
    const int wr = wave >> 1, wc = wave & 1;
    const int row0 = wr * 64;

    f32x4 acc[8][4];
    #pragma unroll
    for (int jt = 0; jt < 8; ++jt)
        #pragma unroll
        for (int mt = 0; mt < 4; ++mt)
            acc[jt][mt] = (f32x4){0.f, 0.f, 0.f, 0.f};

    const _Float16* __restrict__ wp = Wl + lane * 8;

    half8 a[8];
    #pragma unroll
    for (int jt = 0; jt < 8; ++jt)
        a[jt] = *(const half8*)(wp + (size_t)(wc * 2 + (jt >> 2)) * (64 * K)
                                + (jt & 3) * 512);

    half8 b[4];
    #pragma unroll
    for (int mt = 0; mt < 4; ++mt)
        b[mt] = *(const half8*)&Hs[row0 + mt * 16 + m_][quad * 8];

    #pragma unroll
    for (int kk = 0; kk < K; kk += 32) {
        const int s = kk >> 5;
        half8 b2[4];
        if (kk + 32 < K) {
            #pragma unroll
            for (int mt = 0; mt < 4; ++mt)
                b2[mt] = *(const half8*)&Hs[row0 + mt * 16 + m_][kk + 32 + quad * 8];
        }
        #pragma unroll
        for (int jt = 0; jt < 8; ++jt) {
            #pragma unroll
            for (int mt = 0; mt < 4; ++mt)
                acc[jt][mt] = __builtin_amdgcn_mfma_f32_16x16x32_f16(
                    a[jt], b[mt], acc[jt][mt], 0, 0, 0);
            if (kk + 32 < K)   // ring: reload a[jt] for kstep s+1 (~28-MFMA gap)
                a[jt] = *(const half8*)(wp + (size_t)(wc * 2 + (jt >> 2)) * (64 * K)
                                        + ((s + 1) * 4 + (jt & 3)) * 512);
        }
        if (kk + 32 < K) {
            #pragma unroll
            for (int mt = 0; mt < 4; ++mt) b[mt] = b2[mt];
        }
    }
    __syncthreads();   // all waves done reading Hs

    const int jb0 = wc * 128 + quad * 4;
    #pragma unroll
    for (int jt = 0; jt < 8; ++jt) {
        const int jbase = jb0 + jt * 16;
        const float4 w4 = *(const float4*)&parkl[jbase];
        const float4 bb = *(const float4*)&parkl[256 + jbase];
        #pragma unroll
        for (int mt = 0; mt < 4; ++mt) {
            const int node = row0 + mt * 16 + m_;
            const float ev = es[node];
            half4v h;
            h[0] = (_Float16)fmaxf(acc[jt][mt][0] + ev * w4.x + bb.x, 0.f);
            h[1] = (_Float16)fmaxf(acc[jt][mt][1] + ev * w4.y + bb.y, 0.f);
            h[2] = (_Float16)fmaxf(acc[jt][mt][2] + ev * w4.z + bb.z, 0.f);
            h[3] = (_Float16)fmaxf(acc[jt][mt][3] + ev * w4.w + bb.w, 0.f);
            *(half4v*)&Hs[node][jbase] = h;
        }
    }
    __syncthreads();   // Hs writes visible before next layer
}

// ---------------------------------------------------------------------------
// (256,2) kept: VGPR-128 + small spill is the A/B-proven champion config.
// R11's es-aggregation interleave into layer-0's K-loop kept (marginal +).
// ---------------------------------------------------------------------------
__global__ __launch_bounds__(256, 2) void sage_fused(
    const float* __restrict__ node_feat,
    const int* __restrict__ cursor, const unsigned* __restrict__ pairs,
    const float* __restrict__ esh, int nsh,
    const _Float16* __restrict__ Wpack, const float* __restrict__ park,
    float* __restrict__ out) {

    __shared__ _Float16 Hs[128][264];   // +8-half pad
    __shared__ float esp[528];          // 4 shadows @ stride 132 (bank 4s+n)
    __shared__ float es[128];           // combined aggregate
    __shared__ float wf[256];
    __shared__ float red[2][128];

    const int tid  = threadIdx.x;
    const int wave = tid >> 6;
    const int lane = tid & 63;
    const int m_   = lane & 15;
    const int quad = lane >> 4;
    const int wr   = wave >> 1;   // row half (64 nodes)
    const int wc   = wave & 1;    // col half (128 cols)
    const int node0 = blockIdx.x * 128;

    for (int i = tid; i < 528; i += 256) esp[i] = 0.f;

    // hoist the gating cursor load: latency hides under the staging loop
    int cnt = 0;
    if (nsh == 0) cnt = min(cursor[blockIdx.x], CAP);
    __syncthreads();   // esp zeroed

    // ---- stage node_feat tile (fp32 -> fp16) ----
    for (int idx = tid; idx < 128 * 16; idx += 256) {
        const int row = idx >> 4, g = idx & 15;
        int node = node0 + row; if (node >= N_NODES) node = N_NODES - 1;
        const float4* src = (const float4*)(node_feat + (size_t)node * 128 + g * 8);
        const float4 v0 = src[0], v1 = src[1];
        half8 h;
        h[0] = (_Float16)v0.x; h[1] = (_Float16)v0.y;
        h[2] = (_Float16)v0.z; h[3] = (_Float16)v0.w;
        h[4] = (_Float16)v1.x; h[5] = (_Float16)v1.y;
        h[6] = (_Float16)v1.z; h[7] = (_Float16)v1.w;
        *(half8*)&Hs[row][g * 8] = h;
    }
    // fallback path: esh shadow sum (bins-path aggregation lives inside
    // layer-0's K-loop below)
    if (nsh != 0 && tid < 128) {
        int node = node0 + tid; if (node >= N_NODES) node = N_NODES - 1;
        float s = 0.f;
        for (int sh = 0; sh < nsh; ++sh) s += esh[(size_t)sh * SH_STRIDE + node];
        esp[tid] = s;
    }
    __syncthreads();   // Hs staged

    // ---- LAYER 0 (K=128) in 2x2 split, with interleaved edge aggregation --
    {
        const int row0 = wr * 64;
        f32x4 acc[8][4];
        #pragma unroll
        for (int jt = 0; jt < 8; ++jt)
            #pragma unroll
            for (int mt = 0; mt < 4; ++mt)
                acc[jt][mt] = (f32x4){0.f, 0.f, 0.f, 0.f};

        const _Float16* __restrict__ wp = Wpack + lane * 8;
        half8 a[8];
        #pragma unroll
        for (int jt = 0; jt < 8; ++jt)
            a[jt] = *(const half8*)(wp + (size_t)(wc * 2 + (jt >> 2)) * 8192
                                    + (jt & 3) * 512);
        half8 b[4];
        #pragma unroll
        for (int mt = 0; mt < 4; ++mt)
            b[mt] = *(const half8*)&Hs[row0 + mt * 16 + m_][quad * 8];

        const unsigned* __restrict__ pp = pairs + (size_t)blockIdx.x * CAP;
        const int sh = (tid & 3) * 132;

        #pragma unroll
        for (int kk = 0; kk < 128; kk += 32) {
            const int s = kk >> 5;
            half8 b2[4];
            if (kk + 32 < 128) {
                #pragma unroll
                for (int mt = 0; mt < 4; ++mt)
                    b2[mt] = *(const half8*)&Hs[row0 + mt * 16 + m_][kk + 32 + quad * 8];
            }
            // hidden phase: this kstep's slice of the edge aggregation
            if (nsh == 0) {
                for (int i = tid + (s << 8); i < cnt; i += 1024) {
                    const unsigned p = pp[i];
                    atomicAdd(&esp[sh + (p & 127u)],
                              __uint_as_float(p & 0xFFFFFF00u));
                }
            }
            #pragma unroll
            for (int jt = 0; jt < 8; ++jt) {
                #pragma unroll
                for (int mt = 0; mt < 4; ++mt)
                    acc[jt][mt] = __builtin_amdgcn_mfma_f32_16x16x32_f16(
                        a[jt], b[mt], acc[jt][mt], 0, 0, 0);
                if (kk + 32 < 128)
                    a[jt] = *(const half8*)(wp + (size_t)(wc * 2 + (jt >> 2)) * 8192
                                            + ((s + 1) * 4 + (jt & 3)) * 512);
            }
            if (kk + 32 < 128) {
                #pragma unroll
                for (int mt = 0; mt < 4; ++mt) b[mt] = b2[mt];
            }
        }
        __syncthreads();   // K-loop Hs reads done; ALL esp atomics done
        if (tid < 128)
            es[tid] = esp[tid] + esp[132 + tid] + esp[264 + tid] + esp[396 + tid];
        __syncthreads();   // es ready for epilogue

        const int jb0 = wc * 128 + quad * 4;
        #pragma unroll
        for (int jt = 0; jt < 8; ++jt) {
            const int jbase = jb0 + jt * 16;
            const float4 w4 = *(const float4*)&park[jbase];
            const float4 bb = *(const float4*)&park[256 + jbase];
            #pragma unroll
            for (int mt = 0; mt < 4; ++mt) {
                const int node = row0 + mt * 16 + m_;
                const float ev = es[node];
                half4v h;
                h[0] = (_Float16)fmaxf(acc[jt][mt][0] + ev * w4.x + bb.x, 0.f);
                h[1] = (_Float16)fmaxf(acc[jt][mt][1] + ev * w4.y + bb.y, 0.f);
                h[2] = (_Float16)fmaxf(acc[jt][mt][2] + ev * w4.z + bb.z, 0.f);
                h[3] = (_Float16)fmaxf(acc[jt][mt][3] + ev * w4.w + bb.w, 0.f);
                *(half4v*)&Hs[node][jbase] = h;
            }
        }
        __syncthreads();   // Hs writes visible before layer 1
    }

    // layers 1..6: K=256 (in-place Hs, 2 barriers each)
    for (int l = 1; l < 7; ++l)
        layer_mm<256>(Wpack + 32768 + (l - 1) * 65536, Hs, es, park + l * 512,
                      wave, lane, m_, quad);

    // ---- final 256 -> 1 dot (fp32, b128-vectorized LDS reads) ----
    wf[tid] = park[3584 + tid];
    __syncthreads();
    {
        const int row = tid & 127, seg = tid >> 7;
        const _Float16* hp = &Hs[row][seg * 128];
        const float* wpt = &wf[seg * 128];
        float s = 0.f;
        #pragma unroll
        for (int k = 0; k < 16; ++k) {
            const half8 h = *(const half8*)(hp + k * 8);
            const float* w8 = wpt + k * 8;
            s += (float)h[0] * w8[0] + (float)h[1] * w8[1]
               + (float)h[2] * w8[2] + (float)h[3] * w8[3]
               + (float)h[4] * w8[4] + (float)h[5] * w8[5]
               + (float)h[6] * w8[6] + (float)h[7] * w8[7];
        }
        red[seg][row] = s;
    }
    __syncthreads();
    if (tid < 128) {
        const int node = node0 + tid;
        if (node < N_NODES)
            out[node] = red[0][tid] + red[1][tid] + park[3840];
    }
}

// ---------------------------------------------------------------------------
extern "C" void kernel_launch(void* const* d_in, const int* in_sizes, int n_in,
                              void* d_out, int out_size, void* d_ws,
                              size_t ws_size, hipStream_t stream) {
    const float* node_feat = (const float*)d_in[0];
    const float* edge_feat = (const float*)d_in[1];
    const int*   edge_dst  = (const int*)d_in[2];
    const float* W1  = (const float*)d_in[3];  const float* b1  = (const float*)d_in[4];
    const float* Wm1 = (const float*)d_in[5];  const float* bm1 = (const float*)d_in[6];
    const float* Wm2 = (const float*)d_in[7];  const float* bm2 = (const float*)d_in[8];
    const float* Wm3 = (const float*)d_in[9];  const float* bm3 = (const float*)d_in[10];
    const float* Wm4 = (const float*)d_in[11]; const float* bm4 = (const float*)d_in[12];
    const float* Wr1 = (const float*)d_in[13]; const float* br1 = (const float*)d_in[14];
    const float* Wr2 = (const float*)d_in[15]; const float* br2 = (const float*)d_in[16];
    const float* Wr3 = (const float*)d_in[17]; const float* br3 = (const float*)d_in[18];
    float* out = (float*)d_out;

    // ws layout: cursor | Wp | park | pairs (fallback: esh over pairs)
    char* ws = (char*)d_ws;
    int*      cursor = (int*)ws;                           // 4096 B reserved
    _Float16* Wp     = (_Float16*)(ws + 4096);             // 851968 B
    float*    park   = (float*)(ws + 856064);              // 16384 B
    unsigned* pairs  = (unsigned*)(ws + 872448);           // NBUCK*CAP*4 B
    float*    esh    = (float*)(ws + 872448);              // fallback shadows

    const size_t need_bins = 872448 + (size_t)NBUCK * CAP * 4;   // ~16.9 MB
    const bool use_bins = (ws_size >= need_bins);

    const int nblk = (N_NODES + 127) / 128;   // 782

    if (use_bins) {
        hipMemsetAsync(cursor, 0, NBUCK * sizeof(int), stream);
        binpack<<<NBIN + NPK, 512, 0, stream>>>(
            edge_feat, edge_dst, W1, Wm1, Wm2, Wm3, Wm4, Wr1, Wr2,
            b1, bm1, bm2, bm3, bm4, br1, br2, Wr3, br3,
            cursor, pairs, Wp, park, 1);
        sage_fused<<<nblk, 256, 0, stream>>>(node_feat, cursor, pairs,
                                             nullptr, 0, Wp, park, out);
    } else {
        binpack<<<NPK, 512, 0, stream>>>(
            edge_feat, edge_dst, W1, Wm1, Wm2, Wm3, Wm4, Wr1, Wr2,
            b1, bm1, bm2, bm3, bm4, br1, br2, Wr3, br3,
            cursor, pairs, Wp, park, 0);
        hipMemsetAsync(esh, 0, (size_t)4 * SH_STRIDE * 4, stream);
        scatter4<<<3125, 256, 0, stream>>>((const float4*)edge_feat,
                                           (const int4*)edge_dst, esh);
        sage_fused<<<nblk, 256, 0, stream>>>(node_feat, nullptr, nullptr,
                                             esh, 4, Wp, park, out);
    }
}